// Round 2
// baseline (142.843 us; speedup 1.0000x reference)
//
#include <hip/hip_runtime.h>

// SelfAttentionPool, 3-kernel split (round 2).
// R1 (fused, one block/graph) was latency-bound: 49 us, HBM 26%, VALU 13%,
// occupancy 33% -- phase serialization behind __syncthreads with ~2.6
// blocks/CU. The traffic-heavy phases (x.theta, gather) need no per-graph
// coupling, so hoist them into full-device kernels:
//   K1: s[i] = x[i] . theta          (wave/node, 51 MB read, BW-bound)
//   K2: per-graph topology + top-k   (edges 13 MB in / 13 MB out)
//   K3: x_new = x[keep] * sigmoid(z) (wave/row, 41+41 MB, x LLC-warm)
// Numerics identical to the passing R1 kernel (double s/z, double LDS
// scatter atomics) so the top-k selection is unchanged.
//
// Output layout (float32): x_new (80000*128) | edge0 (E) | edge1 (E) | batch_new (80000)
// ws layout: s double[N] | keep int[B*KNUM] | scale float[B*KNUM]  (~1.44 MB)

#define NPG   100
#define EPG   1600
#define KNUM  80
#define FDIM  128

__global__ __launch_bounds__(256)
void k_dot(const float* __restrict__ x, const float* __restrict__ theta,
           double* __restrict__ s, int N)
{
    const int lane = threadIdx.x & 63;
    const int node = (blockIdx.x * 256 + threadIdx.x) >> 6;   // one wave per node
    if (node >= N) return;
    const double th0 = (double)theta[2 * lane];
    const double th1 = (double)theta[2 * lane + 1];
    float2 xv = ((const float2*)(x + (size_t)node * FDIM))[lane];
    double p = (double)xv.x * th0 + (double)xv.y * th1;
    #pragma unroll
    for (int off = 32; off > 0; off >>= 1)
        p += __shfl_down(p, off, 64);
    if (lane == 0) s[node] = p;
}

__global__ __launch_bounds__(256)
void k_topo(const int* __restrict__ ei, const double* __restrict__ s_g,
            float* __restrict__ out, int E_total, int out_x_elems,
            int* __restrict__ keep, float* __restrict__ scale)
{
    const int g    = blockIdx.x;
    const int tid  = threadIdx.x;
    const int base = g * NPG;

    __shared__ int    sh_src[EPG];
    __shared__ int    sh_dst[EPG];
    __shared__ int    sh_deg[NPG];
    __shared__ double sh_dis[NPG];
    __shared__ double sh_s[NPG];
    __shared__ double sh_z[NPG];
    __shared__ int    sh_kept[NPG];
    __shared__ int    sh_newid[NPG];

    if (tid < NPG) {
        sh_deg[tid] = 1;                  // self-loop
        sh_s[tid]   = s_g[base + tid];
    }
    __syncthreads();

    for (int j = tid; j < EPG; j += 256) {
        int s = ei[g * EPG + j]           - base;
        int d = ei[E_total + g * EPG + j] - base;
        sh_src[j] = s;
        sh_dst[j] = d;
        atomicAdd(&sh_deg[s], 1);
    }
    __syncthreads();

    if (tid < NPG) sh_dis[tid] = 1.0 / sqrt((double)sh_deg[tid]);
    __syncthreads();

    if (tid < NPG) sh_z[tid] = sh_s[tid] * sh_dis[tid] * sh_dis[tid];
    __syncthreads();

    for (int j = tid; j < EPG; j += 256) {
        int s = sh_src[j], d = sh_dst[j];
        atomicAdd(&sh_z[d], sh_s[s] * sh_dis[s] * sh_dis[d]);
    }
    __syncthreads();

    // top-k by rank (jax.lax.top_k tie-break: lower index wins)
    if (tid < NPG) {
        double zi = sh_z[tid];
        int rank = 0;
        for (int j = 0; j < NPG; ++j) {
            double zj = sh_z[j];
            rank += (int)((zj > zi) | ((zj == zi) & (j < tid)));
        }
        sh_kept[tid] = (rank < KNUM) ? 1 : 0;
    }
    __syncthreads();

    if (tid < NPG) {
        int r = 0;
        for (int j = 0; j < tid; ++j) r += sh_kept[j];
        if (sh_kept[tid]) {
            int row = g * KNUM + r;
            sh_newid[tid] = row;
            keep[row]  = base + tid;                               // global node id
            scale[row] = (float)(1.0 / (1.0 + exp(-sh_z[tid])));
            out[(size_t)out_x_elems + 2 * (size_t)E_total + row] = (float)g; // batch_new
        } else {
            sh_newid[tid] = -1;
        }
    }
    __syncthreads();

    float* out_e0 = out + out_x_elems;
    float* out_e1 = out_e0 + E_total;
    for (int j = tid; j < EPG; j += 256) {
        int a = sh_newid[sh_src[j]];
        int b = sh_newid[sh_dst[j]];
        bool valid = (a >= 0) && (b >= 0);
        out_e0[g * EPG + j] = valid ? (float)a : -1.0f;
        out_e1[g * EPG + j] = valid ? (float)b : -1.0f;
    }
}

__global__ __launch_bounds__(256)
void k_gather(const float* __restrict__ x, const int* __restrict__ keep,
              const float* __restrict__ scale, float* __restrict__ out, int rows)
{
    const int lane = threadIdx.x & 63;
    const int row  = (blockIdx.x * 256 + threadIdx.x) >> 6;   // one wave per row
    if (row >= rows) return;
    const int   node = keep[row];
    const float sc   = scale[row];
    float2 xv = ((const float2*)(x + (size_t)node * FDIM))[lane];
    float2 o;
    o.x = xv.x * sc;
    o.y = xv.y * sc;
    ((float2*)(out + (size_t)row * FDIM))[lane] = o;
}

extern "C" void kernel_launch(void* const* d_in, const int* in_sizes, int n_in,
                              void* d_out, int out_size, void* d_ws, size_t ws_size,
                              hipStream_t stream)
{
    const float* x     = (const float*)d_in[0];
    const int*   ei    = (const int*)d_in[1];
    const float* theta = (const float*)d_in[3];
    float* out = (float*)d_out;

    const int N = in_sizes[0] / FDIM;        // 100000
    const int E = in_sizes[1] / 2;           // 1600000
    const int B = N / NPG;                   // 1000
    const int out_x_elems = B * KNUM * FDIM; // 10,240,000
    const int rows = B * KNUM;               // 80000

    double* s_ws   = (double*)d_ws;
    int*    keep   = (int*)(s_ws + N);
    float*  scale  = (float*)(keep + rows);

    // K1: s = x . theta  (one wave per node)
    k_dot<<<dim3((N * 64 + 255) / 256), dim3(256), 0, stream>>>(x, theta, s_ws, N);
    // K2: per-graph topology, top-k, edge relabel, batch_new, keep/scale
    k_topo<<<dim3(B), dim3(256), 0, stream>>>(ei, s_ws, out, E, out_x_elems, keep, scale);
    // K3: gather + scale
    k_gather<<<dim3((rows * 64 + 255) / 256), dim3(256), 0, stream>>>(x, keep, scale, out, rows);
}

// Round 3
// 121.067 us; speedup vs baseline: 1.1799x; 1.1799x over previous
//
#include <hip/hip_runtime.h>

// SelfAttentionPool, fused single kernel v2 (round 3).
// R1 (fused) = 49 us kernel, latency-bound (HBM 26%, VALU 13%): shuffle-chain
// dot, serialized phases, shared z atomics. R2 (3-kernel split) regressed
// (+9 us): launch gaps + device drains, same latency chains.
// v2 keeps ONE launch and attacks the per-block critical path:
//  - dot = thread-per-node, 32 independent float4 loads, f64 accumulate,
//    NO shuffles (was 12 dependent ds_bpermute per node)
//  - waves 0-1 dot  ||  waves 2-3 edge load/pack + degree (overlapped)
//  - per-wave private z arrays -> 4x less LDS f64 atomic contention
//  - ballot/popc prefix sum (was O(100) serial LDS loop)
//  - edges packed (src | dst<<16) in LDS, int4/float4 global I/O
// Numerics: same double-precision z pipeline as the passing R1 (ordering
// deltas ~1e-15 << the >=1e-6 gaps R1 proved safe).
//
// Output (float32): x_new (80000*128) | edge0 (E) | edge1 (E) | batch_new (80000)

#define NPG   100
#define EPG   1600
#define KNUM  80
#define FDIM  128

__global__ __launch_bounds__(256)
void sagpool_fused2(const float* __restrict__ x,
                    const int*   __restrict__ ei,
                    const float* __restrict__ theta,
                    float* __restrict__ out,
                    int E_total, int out_x_elems)
{
    const int g    = blockIdx.x;
    const int tid  = threadIdx.x;
    const int wave = tid >> 6;
    const int lane = tid & 63;
    const int base = g * NPG;

    __shared__ int4   sh_edge4[EPG / 4];          // packed: s | (d<<16)
    __shared__ float4 sh_theta4[FDIM / 4];
    __shared__ int    sh_deg[NPG];
    __shared__ double sh_s[NPG];
    __shared__ double sh_dis[NPG];
    __shared__ double sh_a[NPG];                  // s * dis
    __shared__ double sh_zp[4][NPG];              // per-wave private scatter
    __shared__ double sh_z[NPG];
    __shared__ unsigned long long sh_mask[2];
    __shared__ int    sh_newid[NPG];
    __shared__ int    sh_keepnode[KNUM];
    __shared__ float  sh_scale[KNUM];

    int* sh_edge = (int*)sh_edge4;

    if (tid < NPG)      sh_deg[tid] = 1;                      // self-loop
    if (tid < FDIM / 4) sh_theta4[tid] = ((const float4*)theta)[tid];
    for (int i = tid; i < 4 * NPG; i += 256) ((double*)sh_zp)[i] = 0.0;
    __syncthreads();

    if (tid < 128) {
        // ---- waves 0-1: s[i] = x[i] . theta (thread-per-node, no shuffles)
        if (tid < NPG) {
            const float4* xr = (const float4*)(x + (size_t)(base + tid) * FDIM);
            double acc = 0.0;
            #pragma unroll
            for (int k = 0; k < FDIM / 4; ++k) {
                float4 xv = xr[k];
                float4 th = sh_theta4[k];                     // LDS broadcast
                acc += (double)xv.x * th.x + (double)xv.y * th.y
                     + (double)xv.z * th.z + (double)xv.w * th.w;
            }
            sh_s[tid] = acc;
        }
    } else {
        // ---- waves 2-3: stage + pack edges, degree histogram
        const int t2 = tid - 128;
        const int4* src4 = (const int4*)(ei + (size_t)g * EPG);
        const int4* dst4 = (const int4*)(ei + (size_t)E_total + (size_t)g * EPG);
        for (int slot = t2; slot < EPG / 4; slot += 128) {
            int4 s4 = src4[slot];
            int4 d4 = dst4[slot];
            s4.x -= base; s4.y -= base; s4.z -= base; s4.w -= base;
            d4.x -= base; d4.y -= base; d4.z -= base; d4.w -= base;
            int4 p;
            p.x = s4.x | (d4.x << 16);
            p.y = s4.y | (d4.y << 16);
            p.z = s4.z | (d4.z << 16);
            p.w = s4.w | (d4.w << 16);
            sh_edge4[slot] = p;
            atomicAdd(&sh_deg[s4.x], 1);
            atomicAdd(&sh_deg[s4.y], 1);
            atomicAdd(&sh_deg[s4.z], 1);
            atomicAdd(&sh_deg[s4.w], 1);
        }
    }
    __syncthreads();

    if (tid < NPG) {
        double dis = 1.0 / sqrt((double)sh_deg[tid]);
        sh_dis[tid] = dis;
        sh_a[tid]   = sh_s[tid] * dis;
    }
    __syncthreads();

    // ---- z scatter into per-wave private arrays
    {
        double* zp = sh_zp[wave];
        for (int j = tid; j < EPG; j += 256) {
            int p = sh_edge[j];
            int s = p & 0xffff;
            int d = p >> 16;
            atomicAdd(&zp[d], sh_a[s] * sh_dis[d]);
        }
    }
    __syncthreads();

    double zi = 0.0;
    if (tid < NPG) {
        zi = sh_a[tid] * sh_dis[tid]                          // self-loop term
           + sh_zp[0][tid] + sh_zp[1][tid] + sh_zp[2][tid] + sh_zp[3][tid];
        sh_z[tid] = zi;
    }
    __syncthreads();

    // ---- top-k by rank (broadcast LDS reads; tie-break: lower index wins)
    bool kept = false;
    if (tid < NPG) {
        int rank = 0;
        for (int j = 0; j < NPG; ++j) {
            double zj = sh_z[j];
            rank += (int)((zj > zi) | ((zj == zi) & (j < tid)));
        }
        kept = rank < KNUM;
        sh_newid[tid] = -1;
    }
    unsigned long long m = __ballot(kept);
    if (lane == 0 && wave < 2) sh_mask[wave] = m;
    __syncthreads();

    if (kept) {
        int before = (wave == 0)
            ? __popcll(sh_mask[0] & ((1ull << lane) - 1ull))
            : __popcll(sh_mask[0]) + __popcll(sh_mask[1] & ((1ull << lane) - 1ull));
        int row = g * KNUM + before;
        sh_newid[tid]       = row;
        sh_keepnode[before] = tid;
        sh_scale[before]    = (float)(1.0 / (1.0 + exp(-zi)));
        out[(size_t)out_x_elems + 2 * (size_t)E_total + row] = (float)g; // batch_new
    }
    __syncthreads();

    // ---- gather + scale: 80 rows x 128 = 2560 float4, fully coalesced
    for (int idx = tid; idx < KNUM * FDIM / 4; idx += 256) {
        int   row  = idx >> 5;
        int   c    = idx & 31;
        int   node = sh_keepnode[row];
        float sc   = sh_scale[row];
        float4 xv  = ((const float4*)(x + (size_t)(base + node) * FDIM))[c];
        float4 o;
        o.x = xv.x * sc; o.y = xv.y * sc; o.z = xv.z * sc; o.w = xv.w * sc;
        ((float4*)(out + (size_t)(g * KNUM + row) * FDIM))[c] = o;
    }

    // ---- edge relabel, float4 stores
    float* e0 = out + out_x_elems;
    float* e1 = e0 + E_total;
    for (int slot = tid; slot < EPG / 4; slot += 256) {
        int4 p = sh_edge4[slot];
        float4 o0, o1;
        {
            int s = p.x & 0xffff, d = p.x >> 16;
            int a = sh_newid[s], b = sh_newid[d];
            bool v = (a >= 0) && (b >= 0);
            o0.x = v ? (float)a : -1.0f; o1.x = v ? (float)b : -1.0f;
        }
        {
            int s = p.y & 0xffff, d = p.y >> 16;
            int a = sh_newid[s], b = sh_newid[d];
            bool v = (a >= 0) && (b >= 0);
            o0.y = v ? (float)a : -1.0f; o1.y = v ? (float)b : -1.0f;
        }
        {
            int s = p.z & 0xffff, d = p.z >> 16;
            int a = sh_newid[s], b = sh_newid[d];
            bool v = (a >= 0) && (b >= 0);
            o0.z = v ? (float)a : -1.0f; o1.z = v ? (float)b : -1.0f;
        }
        {
            int s = p.w & 0xffff, d = p.w >> 16;
            int a = sh_newid[s], b = sh_newid[d];
            bool v = (a >= 0) && (b >= 0);
            o0.w = v ? (float)a : -1.0f; o1.w = v ? (float)b : -1.0f;
        }
        ((float4*)e0)[(size_t)g * (EPG / 4) + slot] = o0;
        ((float4*)e1)[(size_t)g * (EPG / 4) + slot] = o1;
    }
}

extern "C" void kernel_launch(void* const* d_in, const int* in_sizes, int n_in,
                              void* d_out, int out_size, void* d_ws, size_t ws_size,
                              hipStream_t stream)
{
    const float* x     = (const float*)d_in[0];
    const int*   ei    = (const int*)d_in[1];
    const float* theta = (const float*)d_in[3];
    float* out = (float*)d_out;

    const int N = in_sizes[0] / FDIM;        // 100000
    const int E = in_sizes[1] / 2;           // 1600000
    const int B = N / NPG;                   // 1000
    const int out_x_elems = B * KNUM * FDIM; // 10,240,000

    sagpool_fused2<<<dim3(B), dim3(256), 0, stream>>>(x, ei, theta, out, E, out_x_elems);
}

// Round 4
// 115.707 us; speedup vs baseline: 1.2345x; 1.0463x over previous
//
#include <hip/hip_runtime.h>

// SelfAttentionPool, fused single kernel v3 (round 4).
// History: R1 fused 49us (latency-bound); R2 3-kernel split 58us (launch
// gaps, FAILED direction); R3 fused v2 ~36.5us (thread-per-node dot,
// overlapped staging). v3 attacks the dot phase's request fragmentation:
//  - dot reads are fully COALESCED: 256 threads sweep the graph's 3200
//    contiguous float4 (was: 100 threads each striding its own row ->
//    64 cache lines per wave instruction).
//  - theta fragment per lane is fixed (col4 = lane&31) -> registers, no LDS.
//  - per-iteration 32-lane f64 __shfl_xor tree forms row dots.
//  - edge loads issued before dot loads; edge processing overlaps the
//    in-flight dot loads (compiler waits vmcnt(N), not 0).
// Numerics: same f64 z pipeline as passing R1/R3 (ordering deltas ~1e-15).
//
// Output (float32): x_new (80000*128) | edge0 (E) | edge1 (E) | batch_new (80000)

#define NPG   100
#define EPG   1600
#define KNUM  80
#define FDIM  128
#define NF4   (NPG * FDIM / 4)   // 3200 float4 of x per graph
#define NE4   (EPG / 4)          // 400 int4 per edge row

__global__ __launch_bounds__(256)
void sagpool_fused3(const float* __restrict__ x,
                    const int*   __restrict__ ei,
                    const float* __restrict__ theta,
                    float* __restrict__ out,
                    int E_total, int out_x_elems)
{
    const int g    = blockIdx.x;
    const int tid  = threadIdx.x;
    const int wave = tid >> 6;
    const int lane = tid & 63;
    const int base = g * NPG;

    __shared__ int4   sh_edge4[NE4];              // packed: s | (d<<16)
    __shared__ int    sh_deg[NPG];
    __shared__ double sh_s[NPG];
    __shared__ double sh_dis[NPG];
    __shared__ double sh_a[NPG];                  // s * dis
    __shared__ double sh_zp[4][NPG];              // per-wave private scatter
    __shared__ double sh_z[NPG];
    __shared__ unsigned long long sh_mask[2];
    __shared__ int    sh_newid[NPG];
    __shared__ int    sh_keepnode[KNUM];
    __shared__ float  sh_scale[KNUM];

    int* sh_edge = (int*)sh_edge4;

    // theta fragment: fixed per lane, registers only (coalesced 16B load)
    const float4 th = ((const float4*)theta)[lane & 31];

    if (tid < NPG) sh_deg[tid] = 1;               // self-loop
    for (int i = tid; i < 4 * NPG; i += 256) ((double*)sh_zp)[i] = 0.0;
    __syncthreads();                              // deg/zp init visible

    // ---- issue edge loads first (small), then dot loads (big). Edge
    // processing then only waits on the edge loads (vmcnt(N) keeps the 13
    // dot loads in flight).
    const int4* src4 = (const int4*)(ei + (size_t)g * EPG);
    const int4* dst4 = (const int4*)(ei + (size_t)E_total + (size_t)g * EPG);
    const bool  hasE1 = tid < (NE4 - 256);        // 400 = 256 + 144
    int4 es0 = src4[tid];
    int4 ed0 = dst4[tid];
    int4 es1, ed1;
    if (hasE1) { es1 = src4[256 + tid]; ed1 = dst4[256 + tid]; }

    const float4* xb4 = (const float4*)(x + (size_t)base * FDIM);
    float4 v[12];
    #pragma unroll
    for (int i = 0; i < 12; ++i) v[i] = xb4[i * 256 + tid];
    const bool has13 = tid < (NF4 - 12 * 256);    // last 128 float4
    float4 v12;
    if (has13) v12 = xb4[12 * 256 + tid];

    // ---- process edges (dot loads still in flight)
    {
        int4 s4 = es0, d4 = ed0;
        s4.x -= base; s4.y -= base; s4.z -= base; s4.w -= base;
        d4.x -= base; d4.y -= base; d4.z -= base; d4.w -= base;
        int4 p; p.x = s4.x | (d4.x << 16); p.y = s4.y | (d4.y << 16);
                p.z = s4.z | (d4.z << 16); p.w = s4.w | (d4.w << 16);
        sh_edge4[tid] = p;
        atomicAdd(&sh_deg[s4.x], 1); atomicAdd(&sh_deg[s4.y], 1);
        atomicAdd(&sh_deg[s4.z], 1); atomicAdd(&sh_deg[s4.w], 1);
    }
    if (hasE1) {
        int4 s4 = es1, d4 = ed1;
        s4.x -= base; s4.y -= base; s4.z -= base; s4.w -= base;
        d4.x -= base; d4.y -= base; d4.z -= base; d4.w -= base;
        int4 p; p.x = s4.x | (d4.x << 16); p.y = s4.y | (d4.y << 16);
                p.z = s4.z | (d4.z << 16); p.w = s4.w | (d4.w << 16);
        sh_edge4[256 + tid] = p;
        atomicAdd(&sh_deg[s4.x], 1); atomicAdd(&sh_deg[s4.y], 1);
        atomicAdd(&sh_deg[s4.z], 1); atomicAdd(&sh_deg[s4.w], 1);
    }

    // ---- dot: per-iteration f64 partial + 32-lane xor-tree reduce.
    // idx = i*256 + tid; lanes 0-31 of a wave share one row, 32-63 the next.
    #pragma unroll
    for (int i = 0; i < 12; ++i) {
        double p = (double)v[i].x * th.x + (double)v[i].y * th.y
                 + (double)v[i].z * th.z + (double)v[i].w * th.w;
        #pragma unroll
        for (int m = 1; m <= 16; m <<= 1) p += __shfl_xor(p, m, 64);
        if ((lane & 31) == 0) sh_s[(i * 256 + tid) >> 5] = p;
    }
    if (tid < 128) {                               // rows 96..99 (waves 0-1)
        double p = (double)v12.x * th.x + (double)v12.y * th.y
                 + (double)v12.z * th.z + (double)v12.w * th.w;
        #pragma unroll
        for (int m = 1; m <= 16; m <<= 1) p += __shfl_xor(p, m, 64);
        if ((lane & 31) == 0) sh_s[(12 * 256 + tid) >> 5] = p;
    }
    __syncthreads();                               // edges, deg, s ready

    if (tid < NPG) {
        double dis = 1.0 / sqrt((double)sh_deg[tid]);
        sh_dis[tid] = dis;
        sh_a[tid]   = sh_s[tid] * dis;
    }
    __syncthreads();

    // ---- z scatter into per-wave private arrays
    {
        double* zp = sh_zp[wave];
        for (int j = tid; j < EPG; j += 256) {
            int p = sh_edge[j];
            int s = p & 0xffff;
            int d = p >> 16;
            atomicAdd(&zp[d], sh_a[s] * sh_dis[d]);
        }
    }
    __syncthreads();

    double zi = 0.0;
    if (tid < NPG) {
        zi = sh_a[tid] * sh_dis[tid]               // self-loop term
           + sh_zp[0][tid] + sh_zp[1][tid] + sh_zp[2][tid] + sh_zp[3][tid];
        sh_z[tid] = zi;
    }
    __syncthreads();

    // ---- top-k by rank (tie-break: lower index wins)
    bool kept = false;
    if (tid < NPG) {
        int rank = 0;
        for (int j = 0; j < NPG; ++j) {
            double zj = sh_z[j];
            rank += (int)((zj > zi) | ((zj == zi) & (j < tid)));
        }
        kept = rank < KNUM;
        sh_newid[tid] = -1;
    }
    unsigned long long m = __ballot(kept);
    if (lane == 0 && wave < 2) sh_mask[wave] = m;
    __syncthreads();

    if (kept) {
        int before = (wave == 0)
            ? __popcll(sh_mask[0] & ((1ull << lane) - 1ull))
            : __popcll(sh_mask[0]) + __popcll(sh_mask[1] & ((1ull << lane) - 1ull));
        int row = g * KNUM + before;
        sh_newid[tid]       = row;
        sh_keepnode[before] = tid;
        sh_scale[before]    = (float)(1.0 / (1.0 + exp(-zi)));
        out[(size_t)out_x_elems + 2 * (size_t)E_total + row] = (float)g; // batch_new
    }
    __syncthreads();

    // ---- gather + scale: 80 rows x 32 float4, coalesced (half-wave per row)
    for (int idx = tid; idx < KNUM * FDIM / 4; idx += 256) {
        int   row  = idx >> 5;
        int   c    = idx & 31;
        int   node = sh_keepnode[row];
        float sc   = sh_scale[row];
        float4 xv  = ((const float4*)(x + (size_t)(base + node) * FDIM))[c];
        float4 o;
        o.x = xv.x * sc; o.y = xv.y * sc; o.z = xv.z * sc; o.w = xv.w * sc;
        ((float4*)(out + (size_t)(g * KNUM + row) * FDIM))[c] = o;
    }

    // ---- edge relabel, float4 stores
    float* e0 = out + out_x_elems;
    float* e1 = e0 + E_total;
    for (int slot = tid; slot < NE4; slot += 256) {
        int4 p = sh_edge4[slot];
        float4 o0, o1;
        {
            int s = p.x & 0xffff, d = p.x >> 16;
            int a = sh_newid[s], b = sh_newid[d];
            bool vv = (a >= 0) && (b >= 0);
            o0.x = vv ? (float)a : -1.0f; o1.x = vv ? (float)b : -1.0f;
        }
        {
            int s = p.y & 0xffff, d = p.y >> 16;
            int a = sh_newid[s], b = sh_newid[d];
            bool vv = (a >= 0) && (b >= 0);
            o0.y = vv ? (float)a : -1.0f; o1.y = vv ? (float)b : -1.0f;
        }
        {
            int s = p.z & 0xffff, d = p.z >> 16;
            int a = sh_newid[s], b = sh_newid[d];
            bool vv = (a >= 0) && (b >= 0);
            o0.z = vv ? (float)a : -1.0f; o1.z = vv ? (float)b : -1.0f;
        }
        {
            int s = p.w & 0xffff, d = p.w >> 16;
            int a = sh_newid[s], b = sh_newid[d];
            bool vv = (a >= 0) && (b >= 0);
            o0.w = vv ? (float)a : -1.0f; o1.w = vv ? (float)b : -1.0f;
        }
        ((float4*)e0)[(size_t)g * NE4 + slot] = o0;
        ((float4*)e1)[(size_t)g * NE4 + slot] = o1;
    }
}

extern "C" void kernel_launch(void* const* d_in, const int* in_sizes, int n_in,
                              void* d_out, int out_size, void* d_ws, size_t ws_size,
                              hipStream_t stream)
{
    const float* x     = (const float*)d_in[0];
    const int*   ei    = (const int*)d_in[1];
    const float* theta = (const float*)d_in[3];
    float* out = (float*)d_out;

    const int N = in_sizes[0] / FDIM;        // 100000
    const int E = in_sizes[1] / 2;           // 1600000
    const int B = N / NPG;                   // 1000
    const int out_x_elems = B * KNUM * FDIM; // 10,240,000

    sagpool_fused3<<<dim3(B), dim3(256), 0, stream>>>(x, ei, theta, out, E, out_x_elems);
}

// Round 5
// 110.638 us; speedup vs baseline: 1.2911x; 1.0458x over previous
//
#include <hip/hip_runtime.h>

// SelfAttentionPool, fused single kernel v4 (round 5).
// R1 49us -> R3 ~36.5 -> R4 ~31us (coalesced dot). HBM floor ~16.4us.
// R4 gap: HBM idles while blocks sit in barrier-lockstep compute phases.
// v4: (a) x_new written straight from the dot phase's register-resident x
//     tile (no gather re-read, one fewer barrier/phase);
//     (b) 512 threads/block halves streaming-phase lengths; ~8000 waves
//     keeps the whole grid resident for cross-block overlap.
// Numerics: same f64 z pipeline as passing R1-R4.
//
// Output (float32): x_new (80000*128) | edge0 (E) | edge1 (E) | batch_new (80000)

#define NPG   100
#define EPG   1600
#define KNUM  80
#define FDIM  128
#define BT    512
#define NF4   (NPG * FDIM / 4)   // 3200 float4 of x per graph
#define NE4   (EPG / 4)          // 400 int4 per edge row
#define NCH   (NF4 / BT)         // 6 full chunks, remainder 128

__global__ __launch_bounds__(BT)
void sagpool_fused4(const float* __restrict__ x,
                    const int*   __restrict__ ei,
                    const float* __restrict__ theta,
                    float* __restrict__ out,
                    int E_total, int out_x_elems)
{
    const int g    = blockIdx.x;
    const int tid  = threadIdx.x;
    const int wave = tid >> 6;
    const int lane = tid & 63;
    const int base = g * NPG;

    __shared__ int4   sh_edge4[NE4];              // packed: s | (d<<16)
    __shared__ int    sh_deg[NPG];
    __shared__ double sh_s[NPG];
    __shared__ double sh_dis[NPG];
    __shared__ double sh_a[NPG];                  // s * dis
    __shared__ double sh_zp[8][NPG];              // per-wave private scatter
    __shared__ double sh_z[NPG];
    __shared__ unsigned long long sh_mask[2];
    __shared__ int    sh_newid[NPG];              // global out row, or -1
    __shared__ float  sh_scalen[NPG];             // sigmoid(z), by node
    int* sh_edge = (int*)sh_edge4;

    // theta fragment: fixed per lane (col4 = lane&31), registers only
    const float4 th = ((const float4*)theta)[lane & 31];

    if (tid < NPG) sh_deg[tid] = 1;               // self-loop
    for (int i = tid; i < 8 * NPG; i += BT) ((double*)sh_zp)[i] = 0.0;
    __syncthreads();                              // B1: deg/zp init

    // ---- issue edge loads, then x-tile loads (stay in registers)
    const int4* src4 = (const int4*)(ei + (size_t)g * EPG);
    const int4* dst4 = (const int4*)(ei + (size_t)E_total + (size_t)g * EPG);
    const bool  hasE = tid < NE4;
    int4 es, ed;
    if (hasE) { es = src4[tid]; ed = dst4[tid]; }

    const float4* xb4 = (const float4*)(x + (size_t)base * FDIM);
    float4 v[NCH];
    #pragma unroll
    for (int i = 0; i < NCH; ++i) v[i] = xb4[i * BT + tid];
    const bool hasR = tid < (NF4 - NCH * BT);     // last 128 float4
    float4 vR;
    if (hasR) vR = xb4[NCH * BT + tid];

    // ---- edge pack + degree histogram (x loads still in flight)
    if (hasE) {
        int4 s4 = es, d4 = ed;
        s4.x -= base; s4.y -= base; s4.z -= base; s4.w -= base;
        d4.x -= base; d4.y -= base; d4.z -= base; d4.w -= base;
        int4 p; p.x = s4.x | (d4.x << 16); p.y = s4.y | (d4.y << 16);
                p.z = s4.z | (d4.z << 16); p.w = s4.w | (d4.w << 16);
        sh_edge4[tid] = p;
        atomicAdd(&sh_deg[s4.x], 1); atomicAdd(&sh_deg[s4.y], 1);
        atomicAdd(&sh_deg[s4.z], 1); atomicAdd(&sh_deg[s4.w], 1);
    }

    // ---- dot: f64 partial + 32-lane xor-tree (32 consecutive idx = 1 row)
    #pragma unroll
    for (int i = 0; i < NCH; ++i) {
        double p = (double)v[i].x * th.x + (double)v[i].y * th.y
                 + (double)v[i].z * th.z + (double)v[i].w * th.w;
        #pragma unroll
        for (int m = 1; m <= 16; m <<= 1) p += __shfl_xor(p, m, 64);
        if ((lane & 31) == 0) sh_s[(i * BT + tid) >> 5] = p;
    }
    if (hasR) {
        double p = (double)vR.x * th.x + (double)vR.y * th.y
                 + (double)vR.z * th.z + (double)vR.w * th.w;
        #pragma unroll
        for (int m = 1; m <= 16; m <<= 1) p += __shfl_xor(p, m, 64);
        if ((lane & 31) == 0) sh_s[(NCH * BT + tid) >> 5] = p;
    }
    __syncthreads();                              // B2: edges, deg, s ready

    if (tid < NPG) {
        double dis = 1.0 / sqrt((double)sh_deg[tid]);
        sh_dis[tid] = dis;
        sh_a[tid]   = sh_s[tid] * dis;
    }
    __syncthreads();                              // B3: dis/a ready

    // ---- z scatter into per-wave private arrays (f64 LDS atomics)
    {
        double* zp = sh_zp[wave];
        for (int j = tid; j < EPG; j += BT) {
            int p = sh_edge[j];
            int s = p & 0xffff;
            int d = p >> 16;
            atomicAdd(&zp[d], sh_a[s] * sh_dis[d]);
        }
    }
    __syncthreads();                              // B4: scatter done

    double zi = 0.0;
    if (tid < NPG) {
        zi = sh_a[tid] * sh_dis[tid]              // self-loop term
           + sh_zp[0][tid] + sh_zp[1][tid] + sh_zp[2][tid] + sh_zp[3][tid]
           + sh_zp[4][tid] + sh_zp[5][tid] + sh_zp[6][tid] + sh_zp[7][tid];
        sh_z[tid] = zi;
    }
    __syncthreads();                              // B5: z ready

    // ---- top-k by rank (tie-break: lower index wins)
    bool kept = false;
    if (tid < NPG) {
        int rank = 0;
        for (int j = 0; j < NPG; ++j) {
            double zj = sh_z[j];
            rank += (int)((zj > zi) | ((zj == zi) & (j < tid)));
        }
        kept = rank < KNUM;
        sh_newid[tid] = -1;
    }
    unsigned long long m = __ballot(kept);
    if (lane == 0 && wave < 2) sh_mask[wave] = m;
    __syncthreads();                              // masks + newid init

    if (kept) {
        int before = (wave == 0)
            ? __popcll(sh_mask[0] & ((1ull << lane) - 1ull))
            : __popcll(sh_mask[0]) + __popcll(sh_mask[1] & ((1ull << lane) - 1ull));
        int row = g * KNUM + before;
        sh_newid[tid]   = row;
        sh_scalen[tid]  = (float)(1.0 / (1.0 + exp(-zi)));
        out[(size_t)out_x_elems + 2 * (size_t)E_total + row] = (float)g; // batch_new
    }
    __syncthreads();                              // B6: newid/scalen ready

    // ---- x_new straight from the register-resident tile (no re-read)
    float4* outx = (float4*)out;
    #pragma unroll
    for (int i = 0; i < NCH; ++i) {
        int idx = i * BT + tid;
        int row = idx >> 5;
        int nid = sh_newid[row];
        if (nid >= 0) {
            float sc = sh_scalen[row];
            float4 o;
            o.x = v[i].x * sc; o.y = v[i].y * sc;
            o.z = v[i].z * sc; o.w = v[i].w * sc;
            outx[(size_t)nid * 32 + (idx & 31)] = o;
        }
    }
    if (hasR) {
        int idx = NCH * BT + tid;
        int row = idx >> 5;
        int nid = sh_newid[row];
        if (nid >= 0) {
            float sc = sh_scalen[row];
            float4 o;
            o.x = vR.x * sc; o.y = vR.y * sc;
            o.z = vR.z * sc; o.w = vR.w * sc;
            outx[(size_t)nid * 32 + (idx & 31)] = o;
        }
    }

    // ---- edge relabel, float4 stores
    float* e0 = out + out_x_elems;
    float* e1 = e0 + E_total;
    if (hasE) {
        int4 p = sh_edge4[tid];
        float4 o0, o1;
        {
            int s = p.x & 0xffff, d = p.x >> 16;
            int a = sh_newid[s], b = sh_newid[d];
            bool vv = (a >= 0) && (b >= 0);
            o0.x = vv ? (float)a : -1.0f; o1.x = vv ? (float)b : -1.0f;
        }
        {
            int s = p.y & 0xffff, d = p.y >> 16;
            int a = sh_newid[s], b = sh_newid[d];
            bool vv = (a >= 0) && (b >= 0);
            o0.y = vv ? (float)a : -1.0f; o1.y = vv ? (float)b : -1.0f;
        }
        {
            int s = p.z & 0xffff, d = p.z >> 16;
            int a = sh_newid[s], b = sh_newid[d];
            bool vv = (a >= 0) && (b >= 0);
            o0.z = vv ? (float)a : -1.0f; o1.z = vv ? (float)b : -1.0f;
        }
        {
            int s = p.w & 0xffff, d = p.w >> 16;
            int a = sh_newid[s], b = sh_newid[d];
            bool vv = (a >= 0) && (b >= 0);
            o0.w = vv ? (float)a : -1.0f; o1.w = vv ? (float)b : -1.0f;
        }
        ((float4*)e0)[(size_t)g * NE4 + tid] = o0;
        ((float4*)e1)[(size_t)g * NE4 + tid] = o1;
    }
}

extern "C" void kernel_launch(void* const* d_in, const int* in_sizes, int n_in,
                              void* d_out, int out_size, void* d_ws, size_t ws_size,
                              hipStream_t stream)
{
    const float* x     = (const float*)d_in[0];
    const int*   ei    = (const int*)d_in[1];
    const float* theta = (const float*)d_in[3];
    float* out = (float*)d_out;

    const int N = in_sizes[0] / FDIM;        // 100000
    const int E = in_sizes[1] / 2;           // 1600000
    const int B = N / NPG;                   // 1000
    const int out_x_elems = B * KNUM * FDIM; // 10,240,000

    sagpool_fused4<<<dim3(B), dim3(BT), 0, stream>>>(x, ei, theta, out, E, out_x_elems);
}